// Round 10
// baseline (208.657 us; speedup 1.0000x reference)
//
#include <hip/hip_runtime.h>

#define NNODES 50000
#define NEDGES 800000
#define HD 128            // HEADS*OUT_DIM
#define NEG 0.2f
#define SCAN_BLOCKS ((NNODES + 255) / 256)   // 196
#define MTILE 64
#define LDW 136           // bf16 row stride in LDS
#define MAXD 64           // per-node LDS cache cap in gat_node

typedef __attribute__((ext_vector_type(8))) short short8;
typedef __attribute__((ext_vector_type(4))) float floatx4;

static __device__ inline unsigned short f2bf(float f) {
    unsigned u = __float_as_uint(f);
    return (unsigned short)((u + 0x7FFF + ((u >> 16) & 1)) >> 16);
}
static __device__ inline float bf2f(unsigned short u) {
    return __uint_as_float(((unsigned)u) << 16);
}
static __device__ inline float lrelu_exp(float a) {
    a = (a > 0.f) ? a : NEG * a;
    return __expf(a);
}

// ---------------------------------------------------------------------------
// Kernel 1: h(bf16) = x @ W^T via bf16 MFMA (16x16x32), fused asrc/adst dots.
// W staged fp32->bf16 inline (R6 showed hoisting is neutral). Epilogue
// bounces C through LDS for coalesced 16B h stores.
// ---------------------------------------------------------------------------
__global__ __launch_bounds__(256) void gat_gemm(
    const float* __restrict__ x, const float* __restrict__ W,
    const float* __restrict__ att_src, const float* __restrict__ att_dst,
    unsigned short* __restrict__ h, float* __restrict__ asrc,
    float* __restrict__ adst)
{
    __shared__ unsigned short Wl[128 * LDW];
    __shared__ unsigned short xl[MTILE * LDW];
    const int t = threadIdx.x;
    const int rowBase = blockIdx.x * MTILE;

    for (int idx = t * 4; idx < 128 * 128; idx += 1024) {
        int r = idx >> 7, c = idx & 127;
        float4 v = *(const float4*)(W + idx);
        ushort4 u;
        u.x = f2bf(v.x); u.y = f2bf(v.y); u.z = f2bf(v.z); u.w = f2bf(v.w);
        *(ushort4*)(Wl + r * LDW + c) = u;
    }
    for (int idx = t * 4; idx < MTILE * 128; idx += 1024) {
        int r = idx >> 7, c = idx & 127;
        int g = rowBase + r;
        float4 v = make_float4(0.f, 0.f, 0.f, 0.f);
        if (g < NNODES) v = *(const float4*)(x + (size_t)g * 128 + c);
        ushort4 u;
        u.x = f2bf(v.x); u.y = f2bf(v.y); u.z = f2bf(v.z); u.w = f2bf(v.w);
        *(ushort4*)(xl + r * LDW + c) = u;
    }
    __syncthreads();

    const int wave = t >> 6;
    const int lane = t & 63;
    const int c16  = lane & 15;
    const int quad = lane >> 4;

    floatx4 acc[8];
#pragma unroll
    for (int nt = 0; nt < 8; nt++) acc[nt] = (floatx4)(0.f);

#pragma unroll
    for (int kc = 0; kc < 4; kc++) {
        short8 av = *(const short8*)(xl + (wave * 16 + c16) * LDW + kc * 32 + quad * 8);
#pragma unroll
        for (int nt = 0; nt < 8; nt++) {
            short8 bv = *(const short8*)(Wl + (nt * 16 + c16) * LDW + kc * 32 + quad * 8);
            acc[nt] = __builtin_amdgcn_mfma_f32_16x16x32_bf16(av, bv, acc[nt], 0, 0, 0);
        }
    }

    float As[8], Ad[8];
#pragma unroll
    for (int nt = 0; nt < 8; nt++) {
        As[nt] = att_src[nt * 16 + c16];
        Ad[nt] = att_dst[nt * 16 + c16];
    }
#pragma unroll
    for (int r = 0; r < 4; r++) {
        const int gr = rowBase + wave * 16 + quad * 4 + r;
#pragma unroll
        for (int hh = 0; hh < 4; hh++) {
            float ps = acc[2 * hh][r] * As[2 * hh] + acc[2 * hh + 1][r] * As[2 * hh + 1];
            float pd = acc[2 * hh][r] * Ad[2 * hh] + acc[2 * hh + 1][r] * Ad[2 * hh + 1];
#pragma unroll
            for (int m = 8; m >= 1; m >>= 1) {
                ps += __shfl_xor(ps, m, 64);
                pd += __shfl_xor(pd, m, 64);
            }
            if (c16 == 0 && gr < NNODES) {
                asrc[gr * 4 + hh] = ps;
                adst[gr * 4 + hh] = pd;
            }
        }
    }

    __syncthreads();
#pragma unroll
    for (int r = 0; r < 4; r++) {
        const int lr = wave * 16 + quad * 4 + r;
#pragma unroll
        for (int nt = 0; nt < 8; nt++)
            xl[lr * LDW + nt * 16 + c16] = f2bf(acc[nt][r]);
    }
    __syncthreads();
    for (int idx = t * 8; idx < MTILE * 128; idx += 2048) {
        int r = idx >> 7, c = idx & 127;
        int g = rowBase + r;
        if (g < NNODES)
            *(short8*)(h + (size_t)g * HD + c) = *(const short8*)(xl + r * LDW + c);
    }
}

// ---------------------------------------------------------------------------
// Kernel 2: degree histogram. Returned old value = edge's in-bucket rank.
// ---------------------------------------------------------------------------
__global__ __launch_bounds__(256) void gat_deg(
    const int* __restrict__ ei, int* __restrict__ deg, int* __restrict__ rank)
{
    int e = blockIdx.x * 256 + threadIdx.x;
    int d = ei[NEDGES + e];
    rank[e] = atomicAdd(deg + d, 1);
}

// ---------------------------------------------------------------------------
// Hierarchical exclusive scan of deg -> coff.
// ---------------------------------------------------------------------------
__global__ __launch_bounds__(256) void gat_scan1(
    const int* __restrict__ deg, int* __restrict__ coff, int* __restrict__ bsum)
{
    __shared__ int sh[256];
    const int t = threadIdx.x;
    const int i = blockIdx.x * 256 + t;
    int v = (i < NNODES) ? deg[i] : 0;
    sh[t] = v;
    __syncthreads();
    for (int off = 1; off < 256; off <<= 1) {
        int u = (t >= off) ? sh[t - off] : 0;
        __syncthreads();
        sh[t] += u;
        __syncthreads();
    }
    if (i < NNODES) coff[i] = sh[t] - v;
    if (t == 255) bsum[blockIdx.x] = sh[255];
}

__global__ __launch_bounds__(256) void gat_scan2(int* __restrict__ bsum)
{
    __shared__ int sh[256];
    const int t = threadIdx.x;
    int v = (t < SCAN_BLOCKS) ? bsum[t] : 0;
    sh[t] = v;
    __syncthreads();
    for (int off = 1; off < 256; off <<= 1) {
        int u = (t >= off) ? sh[t - off] : 0;
        __syncthreads();
        sh[t] += u;
        __syncthreads();
    }
    if (t < SCAN_BLOCKS) bsum[t] = sh[t] - v;
}

__global__ __launch_bounds__(256) void gat_scan3(
    int* __restrict__ coff, const int* __restrict__ bsum)
{
    const int i = blockIdx.x * 256 + threadIdx.x;
    if (i < NNODES) coff[i] += bsum[blockIdx.x];
    if (i == 0) coff[NNODES] = NEDGES;
}

// ---------------------------------------------------------------------------
// Kernel 4: CSR fill — 4B src scatter only.
// ---------------------------------------------------------------------------
__global__ __launch_bounds__(256) void gat_fill(
    const int* __restrict__ ei, const int* __restrict__ rank,
    const int* __restrict__ coff, int* __restrict__ csr_src)
{
    int e = blockIdx.x * 256 + threadIdx.x;
    int s = ei[e], d = ei[NEDGES + e];
    csr_src[coff[d] + rank[e]] = s;
}

// ---------------------------------------------------------------------------
// Kernel 5: per-node. Phase 1: gather asrc[src] (L2-resident), compute exp
// weights, sum per head, stash (src,w4) in LDS. Phase 2: normalize + gather
// h rows with 8-way MLP unroll. 32 lanes/node, 8 nodes/block.
// ---------------------------------------------------------------------------
__global__ __launch_bounds__(256) void gat_node(
    const int* __restrict__ coff, const int* __restrict__ csr_src,
    const float* __restrict__ asrc, const float* __restrict__ adst,
    const unsigned short* __restrict__ h, const float* __restrict__ bias,
    float* __restrict__ out, float* __restrict__ ssum)
{
    __shared__ int   sh_src[8 * MAXD];
    __shared__ float sh_w[8 * MAXD * 4];
    int t = threadIdx.x;
    int node8 = t >> 5;
    int n = blockIdx.x * 8 + node8;
    int k = t & 31;
    int head = k >> 3;
    int beg = coff[n], end = coff[n + 1];
    const float4 bn = *(const float4*)(adst + n * 4);   // per-node broadcast

    // phase 1: weight compute + sums + LDS stash
    float4 sum = make_float4(0.f, 0.f, 0.f, 0.f);
    for (int j = beg + k; j < end; j += 32) {
        int s = csr_src[j];
        float4 a = *(const float4*)(asrc + s * 4);
        float4 wv;
        wv.x = lrelu_exp(a.x + bn.x);
        wv.y = lrelu_exp(a.y + bn.y);
        wv.z = lrelu_exp(a.z + bn.z);
        wv.w = lrelu_exp(a.w + bn.w);
        sum.x += wv.x; sum.y += wv.y; sum.z += wv.z; sum.w += wv.w;
        int i = j - beg;
        if (i < MAXD) {
            sh_src[node8 * MAXD + i] = s;
            *(float4*)(sh_w + (node8 * MAXD + i) * 4) = wv;
        }
    }
#pragma unroll
    for (int m = 16; m >= 1; m >>= 1) {
        sum.x += __shfl_xor(sum.x, m, 64);
        sum.y += __shfl_xor(sum.y, m, 64);
        sum.z += __shfl_xor(sum.z, m, 64);
        sum.w += __shfl_xor(sum.w, m, 64);
    }
    if (k == 0) *(float4*)(ssum + n * 4) = sum;
    float rs[4];
    rs[0] = 1.f / (sum.x + 1e-16f);
    rs[1] = 1.f / (sum.y + 1e-16f);
    rs[2] = 1.f / (sum.z + 1e-16f);
    rs[3] = 1.f / (sum.w + 1e-16f);
    const float rsel = rs[head];
    __syncthreads();

    // phase 2: gather h rows; 8 loads in flight per iteration
    const int cnt = end - beg;
    const int lim = (cnt < MAXD) ? cnt : MAXD;
    const int base = node8 * MAXD;
    float4 acc = *(const float4*)(bias + k * 4);
    float4 acc2 = make_float4(0.f, 0.f, 0.f, 0.f);
    int i = 0;
    for (; i + 8 <= lim; i += 8) {
        int sI[8];
        float wI[8];
#pragma unroll
        for (int q = 0; q < 8; q++) {
            sI[q] = sh_src[base + i + q];
            wI[q] = sh_w[(base + i + q) * 4 + head] * rsel;
        }
        ushort4 uI[8];
#pragma unroll
        for (int q = 0; q < 8; q++)
            uI[q] = *(const ushort4*)(h + (size_t)sI[q] * HD + k * 4);
#pragma unroll
        for (int q = 0; q < 8; q += 2) {
            acc.x  = fmaf(bf2f(uI[q].x), wI[q], acc.x);
            acc.y  = fmaf(bf2f(uI[q].y), wI[q], acc.y);
            acc.z  = fmaf(bf2f(uI[q].z), wI[q], acc.z);
            acc.w  = fmaf(bf2f(uI[q].w), wI[q], acc.w);
            acc2.x = fmaf(bf2f(uI[q + 1].x), wI[q + 1], acc2.x);
            acc2.y = fmaf(bf2f(uI[q + 1].y), wI[q + 1], acc2.y);
            acc2.z = fmaf(bf2f(uI[q + 1].z), wI[q + 1], acc2.z);
            acc2.w = fmaf(bf2f(uI[q + 1].w), wI[q + 1], acc2.w);
        }
    }
    for (; i < lim; i++) {
        int s0 = sh_src[base + i];
        float w0 = sh_w[(base + i) * 4 + head] * rsel;
        ushort4 u0 = *(const ushort4*)(h + (size_t)s0 * HD + k * 4);
        acc.x = fmaf(bf2f(u0.x), w0, acc.x);
        acc.y = fmaf(bf2f(u0.y), w0, acc.y);
        acc.z = fmaf(bf2f(u0.z), w0, acc.z);
        acc.w = fmaf(bf2f(u0.w), w0, acc.w);
    }
    for (int j = beg + MAXD; j < end; j++) {        // rare overflow fallback
        int s0 = csr_src[j];
        float4 a = *(const float4*)(asrc + s0 * 4);
        float w4[4];
        w4[0] = lrelu_exp(a.x + bn.x);
        w4[1] = lrelu_exp(a.y + bn.y);
        w4[2] = lrelu_exp(a.z + bn.z);
        w4[3] = lrelu_exp(a.w + bn.w);
        float w0 = w4[head] * rsel;
        ushort4 u0 = *(const ushort4*)(h + (size_t)s0 * HD + k * 4);
        acc.x = fmaf(bf2f(u0.x), w0, acc.x);
        acc.y = fmaf(bf2f(u0.y), w0, acc.y);
        acc.z = fmaf(bf2f(u0.z), w0, acc.z);
        acc.w = fmaf(bf2f(u0.w), w0, acc.w);
    }
    acc.x += acc2.x; acc.y += acc2.y; acc.z += acc2.z; acc.w += acc2.w;
    *(float4*)(out + (size_t)n * HD + k * 4) = acc;
}

// ---------------------------------------------------------------------------
// Kernel 6: alpha_pooled, edge-order; recompute exp from L2-resident arrays.
// ---------------------------------------------------------------------------
__global__ __launch_bounds__(256) void gat_apool(
    const int* __restrict__ ei, const float* __restrict__ asrc,
    const float* __restrict__ adst, const float* __restrict__ ssum,
    float* __restrict__ apool)
{
    int e = blockIdx.x * 256 + threadIdx.x;
    int s = ei[e], d = ei[NEDGES + e];
    float4 a  = *(const float4*)(asrc + s * 4);
    float4 b  = *(const float4*)(adst + d * 4);
    float4 sv = *(const float4*)(ssum + d * 4);
    float w0 = lrelu_exp(a.x + b.x) / (sv.x + 1e-16f);
    float w1 = lrelu_exp(a.y + b.y) / (sv.y + 1e-16f);
    float w2 = lrelu_exp(a.z + b.z) / (sv.z + 1e-16f);
    float w3 = lrelu_exp(a.w + b.w) / (sv.w + 1e-16f);
    apool[e] = 0.25f * (w0 + w1 + w2 + w3);
}

// ---------------------------------------------------------------------------
extern "C" void kernel_launch(void* const* d_in, const int* in_sizes, int n_in,
                              void* d_out, int out_size, void* d_ws, size_t ws_size,
                              hipStream_t stream)
{
    const float* x       = (const float*)d_in[0];
    const int*   ei      = (const int*)d_in[1];
    const float* W       = (const float*)d_in[2];
    const float* att_src = (const float*)d_in[3];
    const float* att_dst = (const float*)d_in[4];
    const float* bias    = (const float*)d_in[5];

    float* out   = (float*)d_out;                    // (N,128)
    float* apool = out + (size_t)NNODES * HD;        // (E,)

    // workspace layout (16B-aligned chunks)
    unsigned short* h = (unsigned short*)d_ws;            // N*128 bf16
    float* asrc   = (float*)(h + (size_t)NNODES * HD);    // N*4
    float* adst   = asrc + NNODES * 4;               // N*4
    float* ssum   = adst + NNODES * 4;               // N*4
    int*   deg    = (int*)(ssum + NNODES * 4);       // N
    int*   coff   = deg + NNODES;                    // N+1
    int*   rank   = coff + NNODES + 1;               // E
    int*   csrsrc = rank + NEDGES;                   // E
    int*   bsum   = csrsrc + NEDGES;                 // SCAN_BLOCKS

    hipMemsetAsync(deg, 0, (size_t)NNODES * sizeof(int), stream);

    gat_gemm<<<(NNODES + MTILE - 1) / MTILE, 256, 0, stream>>>(
        x, W, att_src, att_dst, h, asrc, adst);
    gat_deg<<<NEDGES / 256, 256, 0, stream>>>(ei, deg, rank);
    gat_scan1<<<SCAN_BLOCKS, 256, 0, stream>>>(deg, coff, bsum);
    gat_scan2<<<1, 256, 0, stream>>>(bsum);
    gat_scan3<<<SCAN_BLOCKS, 256, 0, stream>>>(coff, bsum);
    gat_fill<<<NEDGES / 256, 256, 0, stream>>>(ei, rank, coff, csrsrc);
    gat_node<<<NNODES / 8, 256, 0, stream>>>(coff, csrsrc, asrc, adst, h, bias, out, ssum);
    gat_apool<<<NEDGES / 256, 256, 0, stream>>>(ei, asrc, adst, ssum, apool);
}